// Round 13
// baseline (70.363 us; speedup 1.0000x reference)
//
#include <hip/hip_runtime.h>
#include <hip/hip_bf16.h>

#define N_ATOMS   200000
#define D_IN      256
#define D_OUT     256
#define N_SPECIES 4
#define N_STRUCT  2000
#define M_PAD     2048
#define KFLAT     1024
#define SEG_D     8          // ring slots per wave (1 KB rows) -> 8 KB/wave, 32 KB/block
#define SEG_AHEAD 7          // per-wave pipeline depth
#define WT_BLOCKS 512

typedef __attribute__((ext_vector_type(8))) short bf16x8;
typedef __attribute__((ext_vector_type(4))) float f32x4;

typedef const __attribute__((address_space(1))) float gfloat;
typedef __attribute__((address_space(3))) float lfloat;

__device__ inline unsigned short f2bf(float f) {
    unsigned int u = __float_as_uint(f);
    unsigned int r = (u + 0x7fffu + ((u >> 16) & 1u)) >> 16;   // RNE
    return (unsigned short)r;
}

// ---- ws layout (bytes) ----
// 0        : Wt  bf16 [16][256][64]   = 524288   (kbg = s*4 + (k>>6), [n][k'] per block)
// 524288   : S   bf16 [2048][1024]    = 4194304  (rows >= 2000 stay poison, never stored)
// 4718592  : cnt f32  [2048][4]       = 32768

// 64-ary lower_bound over sorted sidx (whole wave participates)
__device__ __forceinline__ int lb64(const int* __restrict__ sidx, int key, int lane) {
    int lo = 0, hi = N_ATOMS;
    while (hi - lo > 64) {
        int step = (hi - lo + 63) >> 6;
        int pos  = lo + lane * step;
        int v    = (pos < hi) ? sidx[pos] : 0x7fffffff;
        unsigned long long m = __ballot(v < key);
        int c = __popcll(m);
        int nlo = (c == 0)  ? lo : (lo + (c - 1) * step + 1);
        int nhi = (c == 64) ? hi : min(hi, lo + c * step);
        lo = nlo; hi = nhi;
    }
    int pos = lo + lane;
    int v   = (pos < hi) ? sidx[pos] : 0x7fffffff;
    unsigned long long m = __ballot(v < key);
    return lo + __popcll(m);
}

// K1 (fused): blocks [0,512) = write-coalesced W transpose; blocks [512,1512)
// = seg, TWO structures per block, TWO waves per structure (contiguous half
// of the rows each). Each wave: R11's proven depth-7 size=16 global_load_lds
// ring in its own 8 KB LDS quarter, counted vmcnt(6), spec masks pre-balloted
// into SGPRs. One barrier at the end: odd wave publishes its partial, even
// wave adds and stores S[g] + cnt[g].
__global__ __launch_bounds__(256) void k_fused(
        const float* __restrict__ x, const float* __restrict__ W,
        const int* __restrict__ spec, const int* __restrict__ sidx,
        unsigned short* __restrict__ Wt, unsigned short* __restrict__ S,
        float* __restrict__ cnt) {

    __shared__ __align__(16) float ring[4][SEG_D][256];   // 32 KB
    __shared__ __align__(16) f32x4 red[2][4][64];         // 8 KB partials
    __shared__ float csl[2][4];

    int t = threadIdx.x;
    int bid = blockIdx.x;

    if (bid < WT_BLOCKS) {
        int gid = bid * 256 + t;
        int o   = gid * 4;
        int kbg = o >> 14;
        int nn  = (o >> 6) & 255;
        int kp  = o & 63;
        int s   = kbg >> 2, kb = kbg & 3;
        int k0  = kb * 64 + kp;
        const float* wb = W + (size_t)s * 65536 + (size_t)k0 * 256 + nn;
        ushort4 u;
        u.x = f2bf(wb[0]);
        u.y = f2bf(wb[256]);
        u.z = f2bf(wb[512]);
        u.w = f2bf(wb[768]);
        *(ushort4*)(Wt + o) = u;
        return;
    }

    int w = t >> 6, lane = t & 63;
    int gi   = w >> 1;                       // structure slot in block (0/1)
    int half = w & 1;                        // which half of the rows
    int g = (bid - WT_BLOCKS) * 2 + gi;      // g < 2000 always (1000 blocks x 2)

    int s0 = lb64(sidx, g,     lane);
    int s1 = lb64(sidx, g + 1, lane);
    int n  = s1 - s0;
    int nh = (n + 1) >> 1;
    int hs = s0 + half * nh;                 // this wave's first row
    int hn = half ? (n - nh) : nh;           // this wave's row count

    f32x4 a0 = (f32x4){0.f,0.f,0.f,0.f}, a1 = a0, a2 = a0, a3 = a0;
    float c0 = 0.f, c1 = 0.f, c2 = 0.f, c3 = 0.f;

    if (hn > 0) {
        int nm1 = hn - 1;
        const float* gp0 = x + (size_t)hs * 256 + lane * 4;

        unsigned long long m0[4], m1[4];
        bool fits = (hn <= 256);
        if (fits) {
#pragma unroll
            for (int c = 0; c < 4; ++c) {
                int sv = spec[hs + min(c * 64 + lane, nm1)];
                m0[c] = __ballot((sv & 1) != 0);
                m1[c] = __ballot((sv & 2) != 0);
            }
        }

        // drain lb64 + spec vector loads so vmcnt counts only ring loads
        asm volatile("s_waitcnt vmcnt(0)" ::: "memory");

#pragma unroll
        for (int j = 0; j < SEG_AHEAD; ++j) {
            int rr = min(j, nm1);
            __builtin_amdgcn_global_load_lds(
                (gfloat*)(gp0 + (size_t)rr * 256),
                (lfloat*)&ring[w][j][0], 16, 0, 0);
        }

#define CONS4(vv, sp)                                                     \
        switch (sp) {                                                     \
            case 0: a0 += vv; c0 += 1.f; break;                           \
            case 1: a1 += vv; c1 += 1.f; break;                           \
            case 2: a2 += vv; c2 += 1.f; break;                           \
            default: a3 += vv; c3 += 1.f; break; }

        if (fits) {
#pragma unroll
            for (int c = 0; c < 4; ++c) {
                int cb = c * 64;
                if (cb < hn) {
                    unsigned long long mm0 = m0[c], mm1 = m1[c];
                    int ce = min(hn, cb + 64);
                    for (int j = cb; j < ce; ++j) {
                        asm volatile("s_waitcnt vmcnt(6)" ::: "memory");
                        f32x4 v = *(const f32x4*)&ring[w][j & (SEG_D - 1)][lane * 4];
                        int r  = j - cb;
                        int sp = (int)((mm0 >> r) & 1ull) | ((int)((mm1 >> r) & 1ull) << 1);
                        CONS4(v, sp);
                        int rr = min(j + SEG_AHEAD, nm1);
                        __builtin_amdgcn_global_load_lds(
                            (gfloat*)(gp0 + (size_t)rr * 256),
                            (lfloat*)&ring[w][(j + SEG_AHEAD) & (SEG_D - 1)][0], 16, 0, 0);
                    }
                }
            }
        } else {
            // safety path (hn > 256): chunked spec reload with full drain
            for (int cb = 0; cb < hn; cb += 64) {
                int spv = spec[hs + min(cb + lane, nm1)];
                asm volatile("s_waitcnt vmcnt(0)" ::: "memory");
                unsigned long long mm0 = __ballot((spv & 1) != 0);
                unsigned long long mm1 = __ballot((spv & 2) != 0);
                int ce = min(hn, cb + 64);
                for (int j = cb; j < ce; ++j) {
                    f32x4 v = *(const f32x4*)&ring[w][j & (SEG_D - 1)][lane * 4];
                    int r  = j - cb;
                    int sp = (int)((mm0 >> r) & 1ull) | ((int)((mm1 >> r) & 1ull) << 1);
                    CONS4(v, sp);
                    int rr = min(j + SEG_AHEAD, nm1);
                    __builtin_amdgcn_global_load_lds(
                        (gfloat*)(gp0 + (size_t)rr * 256),
                        (lfloat*)&ring[w][(j + SEG_AHEAD) & (SEG_D - 1)][0], 16, 0, 0);
                    asm volatile("s_waitcnt vmcnt(6)" ::: "memory");
                }
            }
        }
#undef CONS4
    }

    // combine halves: odd wave publishes, even wave adds + stores
    if (half == 1) {
        red[gi][0][lane] = a0;
        red[gi][1][lane] = a1;
        red[gi][2][lane] = a2;
        red[gi][3][lane] = a3;
        if (lane == 0) {
            csl[gi][0] = c0; csl[gi][1] = c1; csl[gi][2] = c2; csl[gi][3] = c3;
        }
    }
    __syncthreads();
    if (half == 0) {
        a0 += red[gi][0][lane];
        a1 += red[gi][1][lane];
        a2 += red[gi][2][lane];
        a3 += red[gi][3][lane];

        unsigned short* Sg = S + (size_t)g * KFLAT + lane * 4;
        ushort4 u;
        u.x = f2bf(a0[0]); u.y = f2bf(a0[1]); u.z = f2bf(a0[2]); u.w = f2bf(a0[3]);
        *(ushort4*)(Sg + 0)   = u;
        u.x = f2bf(a1[0]); u.y = f2bf(a1[1]); u.z = f2bf(a1[2]); u.w = f2bf(a1[3]);
        *(ushort4*)(Sg + 256) = u;
        u.x = f2bf(a2[0]); u.y = f2bf(a2[1]); u.z = f2bf(a2[2]); u.w = f2bf(a2[3]);
        *(ushort4*)(Sg + 512) = u;
        u.x = f2bf(a3[0]); u.y = f2bf(a3[1]); u.z = f2bf(a3[2]); u.w = f2bf(a3[3]);
        *(ushort4*)(Sg + 768) = u;

        if (lane == 0) {
            float4 c4;
            c4.x = c0 + csl[gi][0];
            c4.y = c1 + csl[gi][1];
            c4.z = c2 + csl[gi][2];
            c4.w = c3 + csl[gi][3];
            *(float4*)(cnt + (size_t)g * 4) = c4;
        }
    }
}

// K2: K-split GEMM, 32 rows x 32 cols per block (512 blocks). Wave w computes
// species-w K-slice; all 4 waves participate in the LDS reduce.
__global__ __launch_bounds__(256) void k_gemm5(
        const unsigned short* __restrict__ S, const float* __restrict__ cnt,
        const float* __restrict__ b, const unsigned short* __restrict__ Wt,
        float* __restrict__ out) {

    __shared__ __align__(16) f32x4 red[4][2][2][64];   // [w][m][n][lane] = 16 KB

    int t = threadIdx.x, w = t >> 6, lane = t & 63;
    int l15 = lane & 15, l4 = lane >> 4;
    int bid = blockIdx.x;
    int g0 = (bid >> 3) * 32;        // 64 row-groups
    int c0 = (bid & 7) * 32;         // 8 col-blocks

    f32x4 acc[2][2];
#pragma unroll
    for (int m = 0; m < 2; ++m)
#pragma unroll
        for (int n = 0; n < 2; ++n) acc[m][n] = (f32x4){0.f, 0.f, 0.f, 0.f};

    const unsigned short* arow = S + (size_t)(g0 + l15) * KFLAT + w * 256 + l4 * 8;
    const unsigned short* wsp  = Wt + (size_t)w * 4 * 16384 + l4 * 8;

#pragma unroll
    for (int kb = 0; kb < 4; ++kb) {
#pragma unroll
        for (int ks = 0; ks < 2; ++ks) {
            bf16x8 af[2];
#pragma unroll
            for (int m = 0; m < 2; ++m)
                af[m] = *(const bf16x8*)(arow + (size_t)m * 16 * KFLAT + kb * 64 + ks * 32);
#pragma unroll
            for (int n = 0; n < 2; ++n) {
                bf16x8 bfr = *(const bf16x8*)(wsp + (size_t)kb * 16384
                                + (size_t)(c0 + n * 16 + l15) * 64 + ks * 32);
#pragma unroll
                for (int m = 0; m < 2; ++m)
                    acc[m][n] = __builtin_amdgcn_mfma_f32_16x16x32_bf16(af[m], bfr, acc[m][n], 0, 0, 0);
            }
        }
    }

#pragma unroll
    for (int m = 0; m < 2; ++m)
#pragma unroll
        for (int n = 0; n < 2; ++n) red[w][m][n][lane] = acc[m][n];
    __syncthreads();

    {
        int mw = w >> 1, nw = w & 1;
        f32x4 sum = red[0][mw][nw][lane] + red[1][mw][nw][lane]
                  + red[2][mw][nw][lane] + red[3][mw][nw][lane];

        int col = c0 + nw * 16 + l15;
        float bv[4];
#pragma unroll
        for (int s = 0; s < 4; ++s) bv[s] = b[s * 256 + col];

#pragma unroll
        for (int r = 0; r < 4; ++r) {
            int grow = g0 + mw * 16 + l4 * 4 + r;
            if (grow < N_STRUCT) {
                float4 c4 = *(const float4*)(cnt + (size_t)grow * 4);
                out[(size_t)grow * 256 + col] =
                    sum[r] + c4.x * bv[0] + c4.y * bv[1]
                           + c4.z * bv[2] + c4.w * bv[3];
            }
        }
    }
}

extern "C" void kernel_launch(void* const* d_in, const int* in_sizes, int n_in,
                              void* d_out, int out_size, void* d_ws, size_t ws_size,
                              hipStream_t stream) {
    const float* x    = (const float*)d_in[0];
    const float* W    = (const float*)d_in[1];
    const float* b    = (const float*)d_in[2];
    const int* spec   = (const int*)d_in[3];
    const int* sidx   = (const int*)d_in[4];
    float* out        = (float*)d_out;

    char* ws = (char*)d_ws;
    unsigned short* Wt = (unsigned short*)ws;               // 524288 B
    unsigned short* S  = (unsigned short*)(ws + 524288);    // 4194304 B
    float* cnt  = (float*)(ws + 4718592);                   // 32768 B

    k_fused<<<WT_BLOCKS + (N_STRUCT + 1) / 2, 256, 0, stream>>>(x, W, spec, sidx, Wt, S, cnt);
    k_gemm5<<<(M_PAD / 32) * (D_OUT / 32), 256, 0, stream>>>(S, cnt, b, Wt, out);
}

// Round 14
// 50.727 us; speedup vs baseline: 1.3871x; 1.3871x over previous
//
#include <hip/hip_runtime.h>
#include <hip/hip_bf16.h>

#define N_ATOMS   200000
#define D_IN      256
#define D_OUT     256
#define N_SPECIES 4
#define N_STRUCT  2000
#define M_PAD     2048
#define KFLAT     1024
#define SEG_D     8          // ring slots per wave -> 32 KB/block (R11 proven)
#define SEG_AHEAD 7          // pipeline depth
#define WT_BLOCKS 512
#define SEG_BLOCKS ((N_STRUCT + 3) / 4)   // 500

typedef __attribute__((ext_vector_type(8))) short bf16x8;
typedef __attribute__((ext_vector_type(4))) float f32x4;

typedef const __attribute__((address_space(1))) float gfloat;
typedef __attribute__((address_space(3))) float lfloat;

__device__ inline unsigned short f2bf(float f) {
    unsigned int u = __float_as_uint(f);
    unsigned int r = (u + 0x7fffu + ((u >> 16) & 1u)) >> 16;   // RNE
    return (unsigned short)r;
}

// ---- ws layout (bytes) ----
// 0        : Wt  bf16 [16][256][64]   = 524288   (kbg = s*4 + (k>>6), [n][k'] per block)
// 524288   : S   bf16 [2048][1024]    = 4194304  (rows >= 2000 stay poison, never stored)
// 4718592  : cnt f32  [2048][4]       = 32768

// 64-ary lower_bound over sorted sidx (whole wave participates)
__device__ __forceinline__ int lb64(const int* __restrict__ sidx, int key, int lane) {
    int lo = 0, hi = N_ATOMS;
    while (hi - lo > 64) {
        int step = (hi - lo + 63) >> 6;
        int pos  = lo + lane * step;
        int v    = (pos < hi) ? sidx[pos] : 0x7fffffff;
        unsigned long long m = __ballot(v < key);
        int c = __popcll(m);
        int nlo = (c == 0)  ? lo : (lo + (c - 1) * step + 1);
        int nhi = (c == 64) ? hi : min(hi, lo + c * step);
        lo = nlo; hi = nhi;
    }
    int pos = lo + lane;
    int v   = (pos < hi) ? sidx[pos] : 0x7fffffff;
    unsigned long long m = __ballot(v < key);
    return lo + __popcll(m);
}

// K1 (fused): blocks [0,512) = write-coalesced W transpose; blocks [512,1012)
// = seg (R11 structure exactly: one wave = one structure, depth-7 size=16
// global_load_lds ring, counted vmcnt(6), spec masks pre-balloted into SGPRs,
// no barriers). NEW: bijective XCD swizzle on the seg block index so
// consecutive x address ranges stay on one XCD's L2 (HBM locality, T1/m204).
__global__ __launch_bounds__(256) void k_fused(
        const float* __restrict__ x, const float* __restrict__ W,
        const int* __restrict__ spec, const int* __restrict__ sidx,
        unsigned short* __restrict__ Wt, unsigned short* __restrict__ S,
        float* __restrict__ cnt) {

    __shared__ __align__(16) float ring[4][SEG_D][256];   // 32 KB

    int t = threadIdx.x;
    int bid = blockIdx.x;

    if (bid < WT_BLOCKS) {
        int gid = bid * 256 + t;
        int o   = gid * 4;
        int kbg = o >> 14;
        int nn  = (o >> 6) & 255;
        int kp  = o & 63;
        int s   = kbg >> 2, kb = kbg & 3;
        int k0  = kb * 64 + kp;
        const float* wb = W + (size_t)s * 65536 + (size_t)k0 * 256 + nn;
        ushort4 u;
        u.x = f2bf(wb[0]);
        u.y = f2bf(wb[256]);
        u.z = f2bf(wb[512]);
        u.w = f2bf(wb[768]);
        *(ushort4*)(Wt + o) = u;
        return;
    }

    int w = t >> 6, lane = t & 63;

    // bijective XCD swizzle over SEG_BLOCKS=500 (q=62, r=4; m204 variant)
    int sb  = bid - WT_BLOCKS;
    int q   = SEG_BLOCKS >> 3, r = SEG_BLOCKS & 7;
    int xcd = sb & 7, idx = sb >> 3;
    int swz = (xcd < r) ? (xcd * (q + 1) + idx)
                        : (r * (q + 1) + (xcd - r) * q + idx);
    int g = swz * 4 + w;
    if (g >= N_STRUCT) return;

    int s0 = lb64(sidx, g,     lane);
    int s1 = lb64(sidx, g + 1, lane);
    int n  = s1 - s0;

    f32x4 a0 = (f32x4){0.f,0.f,0.f,0.f}, a1 = a0, a2 = a0, a3 = a0;
    float c0 = 0.f, c1 = 0.f, c2 = 0.f, c3 = 0.f;

    if (n > 0) {
        int nm1 = n - 1;
        const float* gp0 = x + (size_t)s0 * 256 + lane * 4;

        unsigned long long m0[4], m1[4];
        bool fits = (n <= 256);
        if (fits) {
#pragma unroll
            for (int c = 0; c < 4; ++c) {
                int sv = spec[s0 + min(c * 64 + lane, nm1)];
                m0[c] = __ballot((sv & 1) != 0);
                m1[c] = __ballot((sv & 2) != 0);
            }
        }

        // drain lb64 + spec vector loads so vmcnt counts only ring loads
        asm volatile("s_waitcnt vmcnt(0)" ::: "memory");

#pragma unroll
        for (int j = 0; j < SEG_AHEAD; ++j) {
            int rr = min(j, nm1);
            __builtin_amdgcn_global_load_lds(
                (gfloat*)(gp0 + (size_t)rr * 256),
                (lfloat*)&ring[w][j][0], 16, 0, 0);
        }

#define CONS4(vv, sp)                                                     \
        switch (sp) {                                                     \
            case 0: a0 += vv; c0 += 1.f; break;                           \
            case 1: a1 += vv; c1 += 1.f; break;                           \
            case 2: a2 += vv; c2 += 1.f; break;                           \
            default: a3 += vv; c3 += 1.f; break; }

        if (fits) {
#pragma unroll
            for (int c = 0; c < 4; ++c) {
                int cb = c * 64;
                if (cb < n) {
                    unsigned long long mm0 = m0[c], mm1 = m1[c];
                    int ce = min(n, cb + 64);
                    for (int j = cb; j < ce; ++j) {
                        asm volatile("s_waitcnt vmcnt(6)" ::: "memory");
                        f32x4 v = *(const f32x4*)&ring[w][j & (SEG_D - 1)][lane * 4];
                        int r2 = j - cb;
                        int sp = (int)((mm0 >> r2) & 1ull) | ((int)((mm1 >> r2) & 1ull) << 1);
                        CONS4(v, sp);
                        int rr = min(j + SEG_AHEAD, nm1);
                        __builtin_amdgcn_global_load_lds(
                            (gfloat*)(gp0 + (size_t)rr * 256),
                            (lfloat*)&ring[w][(j + SEG_AHEAD) & (SEG_D - 1)][0], 16, 0, 0);
                    }
                }
            }
        } else {
            // rare tail path (n > 256): chunked spec reload with full drain
            for (int cb = 0; cb < n; cb += 64) {
                int spv = spec[s0 + min(cb + lane, nm1)];
                asm volatile("s_waitcnt vmcnt(0)" ::: "memory");
                unsigned long long mm0 = __ballot((spv & 1) != 0);
                unsigned long long mm1 = __ballot((spv & 2) != 0);
                int ce = min(n, cb + 64);
                for (int j = cb; j < ce; ++j) {
                    f32x4 v = *(const f32x4*)&ring[w][j & (SEG_D - 1)][lane * 4];
                    int r2 = j - cb;
                    int sp = (int)((mm0 >> r2) & 1ull) | ((int)((mm1 >> r2) & 1ull) << 1);
                    CONS4(v, sp);
                    int rr = min(j + SEG_AHEAD, nm1);
                    __builtin_amdgcn_global_load_lds(
                        (gfloat*)(gp0 + (size_t)rr * 256),
                        (lfloat*)&ring[w][(j + SEG_AHEAD) & (SEG_D - 1)][0], 16, 0, 0);
                    asm volatile("s_waitcnt vmcnt(6)" ::: "memory");
                }
            }
        }
#undef CONS4
    }

    unsigned short* Sg = S + (size_t)g * KFLAT + lane * 4;
    ushort4 u;
    u.x = f2bf(a0[0]); u.y = f2bf(a0[1]); u.z = f2bf(a0[2]); u.w = f2bf(a0[3]);
    *(ushort4*)(Sg + 0)   = u;
    u.x = f2bf(a1[0]); u.y = f2bf(a1[1]); u.z = f2bf(a1[2]); u.w = f2bf(a1[3]);
    *(ushort4*)(Sg + 256) = u;
    u.x = f2bf(a2[0]); u.y = f2bf(a2[1]); u.z = f2bf(a2[2]); u.w = f2bf(a2[3]);
    *(ushort4*)(Sg + 512) = u;
    u.x = f2bf(a3[0]); u.y = f2bf(a3[1]); u.z = f2bf(a3[2]); u.w = f2bf(a3[3]);
    *(ushort4*)(Sg + 768) = u;

    if (lane == 0) {
        float4 c4; c4.x = c0; c4.y = c1; c4.z = c2; c4.w = c3;
        *(float4*)(cnt + (size_t)g * 4) = c4;
    }
}

// K2: K-split GEMM, 32 rows x 32 cols per block (512 blocks). Wave w computes
// species-w K-slice; all 4 waves participate in the LDS reduce.
__global__ __launch_bounds__(256) void k_gemm5(
        const unsigned short* __restrict__ S, const float* __restrict__ cnt,
        const float* __restrict__ b, const unsigned short* __restrict__ Wt,
        float* __restrict__ out) {

    __shared__ __align__(16) f32x4 red[4][2][2][64];   // [w][m][n][lane] = 16 KB

    int t = threadIdx.x, w = t >> 6, lane = t & 63;
    int l15 = lane & 15, l4 = lane >> 4;
    int bid = blockIdx.x;
    int g0 = (bid >> 3) * 32;        // 64 row-groups
    int c0 = (bid & 7) * 32;         // 8 col-blocks

    f32x4 acc[2][2];
#pragma unroll
    for (int m = 0; m < 2; ++m)
#pragma unroll
        for (int n = 0; n < 2; ++n) acc[m][n] = (f32x4){0.f, 0.f, 0.f, 0.f};

    const unsigned short* arow = S + (size_t)(g0 + l15) * KFLAT + w * 256 + l4 * 8;
    const unsigned short* wsp  = Wt + (size_t)w * 4 * 16384 + l4 * 8;

#pragma unroll
    for (int kb = 0; kb < 4; ++kb) {
#pragma unroll
        for (int ks = 0; ks < 2; ++ks) {
            bf16x8 af[2];
#pragma unroll
            for (int m = 0; m < 2; ++m)
                af[m] = *(const bf16x8*)(arow + (size_t)m * 16 * KFLAT + kb * 64 + ks * 32);
#pragma unroll
            for (int n = 0; n < 2; ++n) {
                bf16x8 bfr = *(const bf16x8*)(wsp + (size_t)kb * 16384
                                + (size_t)(c0 + n * 16 + l15) * 64 + ks * 32);
#pragma unroll
                for (int m = 0; m < 2; ++m)
                    acc[m][n] = __builtin_amdgcn_mfma_f32_16x16x32_bf16(af[m], bfr, acc[m][n], 0, 0, 0);
            }
        }
    }

#pragma unroll
    for (int m = 0; m < 2; ++m)
#pragma unroll
        for (int n = 0; n < 2; ++n) red[w][m][n][lane] = acc[m][n];
    __syncthreads();

    {
        int mw = w >> 1, nw = w & 1;
        f32x4 sum = red[0][mw][nw][lane] + red[1][mw][nw][lane]
                  + red[2][mw][nw][lane] + red[3][mw][nw][lane];

        int col = c0 + nw * 16 + l15;
        float bv[4];
#pragma unroll
        for (int s = 0; s < 4; ++s) bv[s] = b[s * 256 + col];

#pragma unroll
        for (int r = 0; r < 4; ++r) {
            int grow = g0 + mw * 16 + l4 * 4 + r;
            if (grow < N_STRUCT) {
                float4 c4 = *(const float4*)(cnt + (size_t)grow * 4);
                out[(size_t)grow * 256 + col] =
                    sum[r] + c4.x * bv[0] + c4.y * bv[1]
                           + c4.z * bv[2] + c4.w * bv[3];
            }
        }
    }
}

extern "C" void kernel_launch(void* const* d_in, const int* in_sizes, int n_in,
                              void* d_out, int out_size, void* d_ws, size_t ws_size,
                              hipStream_t stream) {
    const float* x    = (const float*)d_in[0];
    const float* W    = (const float*)d_in[1];
    const float* b    = (const float*)d_in[2];
    const int* spec   = (const int*)d_in[3];
    const int* sidx   = (const int*)d_in[4];
    float* out        = (float*)d_out;

    char* ws = (char*)d_ws;
    unsigned short* Wt = (unsigned short*)ws;               // 524288 B
    unsigned short* S  = (unsigned short*)(ws + 524288);    // 4194304 B
    float* cnt  = (float*)(ws + 4718592);                   // 32768 B

    k_fused<<<WT_BLOCKS + SEG_BLOCKS, 256, 0, stream>>>(x, W, spec, sidx, Wt, S, cnt);
    k_gemm5<<<(M_PAD / 32) * (D_OUT / 32), 256, 0, stream>>>(S, cnt, b, Wt, out);
}